// Round 5
// baseline (246.878 us; speedup 1.0000x reference)
//
#include <hip/hip_runtime.h>
#include <hip/hip_bf16.h>

#define B_ 4
#define T_ 2048
#define C_ 1024
#define H_ 16
#define D_ 64
#define M_ (B_*T_)   // 8192

typedef __bf16 bf16x8 __attribute__((ext_vector_type(8)));
typedef float  f32x4  __attribute__((ext_vector_type(4)));
typedef float  f32x16 __attribute__((ext_vector_type(16)));

__device__ __forceinline__ unsigned short f2bf(float f) {
  unsigned u = __builtin_bit_cast(unsigned, f);
  u += 0x7FFF + ((u >> 16) & 1);   // round-to-nearest-even
  return (unsigned short)(u >> 16);
}

__device__ __forceinline__ void gload_lds16(const void* g, void* l) {
  __builtin_amdgcn_global_load_lds(
      (const __attribute__((address_space(1))) void*)g,
      (__attribute__((address_space(3))) void*)l, 16, 0, 0);
}

// ---------------- conversion: f32 -> bf16 (vectorized) ----------------
__global__ void cvt_f32_bf16(const float* __restrict__ in,
                             unsigned short* __restrict__ out, int n4) {
  int i = blockIdx.x * blockDim.x + threadIdx.x;
  if (i < n4) {
    float4 v = ((const float4*)in)[i];
    ushort4 o;
    o.x = f2bf(v.x); o.y = f2bf(v.y); o.z = f2bf(v.z); o.w = f2bf(v.w);
    ((ushort4*)out)[i] = o;
  }
}

// ------------- weight transpose + convert: W[K][N] f32 -> Wt[N][K] bf16 -------------
__global__ void transpose_cvt(const float* __restrict__ w0, const float* __restrict__ w1,
                              const float* __restrict__ w2, const float* __restrict__ w3,
                              unsigned short* __restrict__ t0, unsigned short* __restrict__ t1,
                              unsigned short* __restrict__ t2, unsigned short* __restrict__ t3) {
  __shared__ float tile[32][33];
  const float* src; unsigned short* dst;
  switch (blockIdx.z) {
    case 0: src = w0; dst = t0; break;
    case 1: src = w1; dst = t1; break;
    case 2: src = w2; dst = t2; break;
    default: src = w3; dst = t3; break;
  }
  int bx = blockIdx.x * 32;  // n base
  int by = blockIdx.y * 32;  // k base
  int tx = threadIdx.x, ty = threadIdx.y;
  #pragma unroll
  for (int j = 0; j < 4; ++j)
    tile[ty + 8*j][tx] = src[(size_t)(by + ty + 8*j) * C_ + bx + tx];
  __syncthreads();
  #pragma unroll
  for (int j = 0; j < 4; ++j)
    dst[(size_t)(bx + ty + 8*j) * C_ + by + tx] = f2bf(tile[tx][ty + 8*j]);
}

// ---------------- bf16 MFMA GEMM: A[M][K] * Bt[N][K]^T + bias, then *oscale ----------------
// MODE 0: store bf16, head-split [B][H][T][D]
// MODE 1: store bf16, head-split transposed [B][H][D][T] with key-permuted order
//         (t bits 2<->3 swapped) for direct PV A-fragment reads
// MODE 2: store f32 [M][N]                                 (final output)
template<int MODE>
__global__ __launch_bounds__(256, 2)
void gemm_bf16(const unsigned short* __restrict__ A,
               const unsigned short* __restrict__ Bt,
               const float* __restrict__ bias,
               void* __restrict__ Cout, int K, int N, float oscale)
{
  __shared__ unsigned short lsA[128 * 64];
  __shared__ unsigned short lsB[128 * 64];
  const int wave = threadIdx.x >> 6;
  const int lane = threadIdx.x & 63;
  const int rowBase = blockIdx.y * 128;
  const int colBase = blockIdx.x * 128;
  const int rowOff = (wave >> 1) * 64;
  const int colOff = (wave & 1) * 64;
  const int lr = lane & 15;
  const int lg = lane >> 4;

  f32x4 acc[4][4] = {};

  const int chunkRow = lane >> 3;
  const int srcColE  = (((lane & 7) ^ (lane >> 3)) * 8);

  for (int k0 = 0; k0 < K; k0 += 64) {
    #pragma unroll
    for (int c = 0; c < 4; ++c) {
      int chunk = c * 4 + wave;
      int r = chunk * 8 + chunkRow;
      gload_lds16(A  + (size_t)(rowBase + r) * K + k0 + srcColE, &lsA[chunk * 512]);
      gload_lds16(Bt + (size_t)(colBase + r) * K + k0 + srcColE, &lsB[chunk * 512]);
    }
    __syncthreads();
    #pragma unroll
    for (int kk = 0; kk < 2; ++kk) {
      bf16x8 af[4], bfr[4];
      const int kbyte = (kk * 32 + lg * 8) * 2;
      #pragma unroll
      for (int m = 0; m < 4; ++m) {
        int row = rowOff + m * 16 + lr;
        af[m] = *(const bf16x8*)((const char*)lsA + row * 128 + (kbyte ^ ((row & 7) << 4)));
      }
      #pragma unroll
      for (int n = 0; n < 4; ++n) {
        int row = colOff + n * 16 + lr;
        bfr[n] = *(const bf16x8*)((const char*)lsB + row * 128 + (kbyte ^ ((row & 7) << 4)));
      }
      #pragma unroll
      for (int m = 0; m < 4; ++m)
        #pragma unroll
        for (int n = 0; n < 4; ++n)
          acc[m][n] = __builtin_amdgcn_mfma_f32_16x16x32_bf16(af[m], bfr[n], acc[m][n], 0, 0, 0);
    }
    __syncthreads();
  }

  #pragma unroll
  for (int m = 0; m < 4; ++m) {
    int row0 = rowBase + rowOff + m * 16 + lg * 4;
    #pragma unroll
    for (int n = 0; n < 4; ++n) {
      int col = colBase + colOff + n * 16 + lr;
      float bs = bias[col];
      if (MODE == 1) {
        int b = row0 >> 11, t = row0 & 2047;
        int t2 = (t & ~12) | ((t & 4) << 1) | ((t & 8) >> 1);  // key-perm (bits 2<->3)
        int h = col >> 6, d = col & 63;
        ushort4 o;
        o.x = f2bf((acc[m][n][0] + bs) * oscale);
        o.y = f2bf((acc[m][n][1] + bs) * oscale);
        o.z = f2bf((acc[m][n][2] + bs) * oscale);
        o.w = f2bf((acc[m][n][3] + bs) * oscale);
        *(ushort4*)((unsigned short*)Cout + (((size_t)b * H_ + h) * D_ + d) * T_ + t2) = o;
      } else {
        #pragma unroll
        for (int j = 0; j < 4; ++j) {
          float v = (acc[m][n][j] + bs) * oscale;
          int r = row0 + j;
          if (MODE == 2) {
            ((float*)Cout)[(size_t)r * N + col] = v;
          } else {
            int b = r >> 11, t = r & 2047;
            int h = col >> 6, d = col & 63;
            ((unsigned short*)Cout)[((((size_t)b * H_ + h) * T_ + t) << 6) + d] = f2bf(v);
          }
        }
      }
    }
  }
}

// ---------------- causal flash attention: barrier-free, register-direct fragments --------
// q,k: [B][H][T][D] bf16 (q pre-scaled by log2e/sqrt(D)); vp: [B][H][D][T] bf16 key-permuted
// (bits 2<->3 of t swapped) so global layout == MFMA A-fragment layout; y: [B][T][C] bf16.
// One wave per 32-row q-tile; no LDS, no __syncthreads. Per 32-key tile: K/V fragments are
// direct global_load_dwordx4 (the layouts match the fragments), software-pipelined one tile
// ahead in named register sets (A/B). Swapped QK^T / PV keeps softmax fully lane-local.
__global__ __launch_bounds__(256, 2)
void attn5(const unsigned short* __restrict__ q,
           const unsigned short* __restrict__ k,
           const unsigned short* __restrict__ vp,
           unsigned short* __restrict__ y)
{
  const int wave = threadIdx.x >> 6;
  const int lane = threadIdx.x & 63;
  const int col  = lane & 31;   // query index within 32 (and K-row / V-d-row index)
  const int hi   = lane >> 5;

  // block decode: XCD-local heads (bid&7 tracks the usual bid%8 XCD round-robin),
  // longest q-tiles dispatched first, 4 consecutive qt per block (one per wave).
  const int bid = blockIdx.x;            // 0..1023
  const int xcd = bid & 7;
  const int idx = bid >> 3;              // 0..127
  const int qtg = 15 - (idx >> 3);       // 15..0  (longest first)
  const int bh  = xcd * 8 + (idx & 7);   // 8 heads per XCD
  const int b = bh >> 4, h = bh & 15;
  const int qt  = qtg * 4 + wave;        // 0..63
  const int q0  = qt * 32;
  const int ntiles = qt + 1;             // 32-key tiles

  const unsigned short* qh = q  + (size_t)bh * T_ * D_;
  const unsigned short* kh = k  + (size_t)bh * T_ * D_;
  const unsigned short* vh = vp + (size_t)bh * D_ * T_;

  // Q B-fragments: bqf[ks] = Q[q0+col][ks*16 + hi*8 + e]
  bf16x8 bqf[4];
  {
    const unsigned short* qrow = qh + (size_t)(q0 + col) * D_ + hi * 8;
    #pragma unroll
    for (int ks = 0; ks < 4; ++ks) bqf[ks] = *(const bf16x8*)(qrow + ks * 16);
  }

  f32x16 ot0 = {}, ot1 = {};
  float m = -INFINITY, l = 0.f;

  bf16x8 kfA[4], vfA[4], kfB[4], vfB[4];

  auto LOADK = [&](int t, bf16x8* kf) {
    const unsigned short* kr = kh + (size_t)(t * 32 + col) * D_ + hi * 8;
    #pragma unroll
    for (int ks = 0; ks < 4; ++ks) kf[ks] = *(const bf16x8*)(kr + ks * 16);
  };
  auto LOADV = [&](int t, bf16x8* vf) {
    #pragma unroll
    for (int dt = 0; dt < 2; ++dt) {
      const unsigned short* vr = vh + (size_t)(dt * 32 + col) * T_ + t * 32 + hi * 8;
      #pragma unroll
      for (int ks = 0; ks < 2; ++ks) vf[dt * 2 + ks] = *(const bf16x8*)(vr + ks * 16);
    }
  };

  auto COMPUTE = [&](int t, bool diag, const bf16x8* kf, const bf16x8* vf) {
    // ---- QK^T: S^T[key][q] ----
    f32x16 st = {};
    __builtin_amdgcn_s_setprio(1);
    #pragma unroll
    for (int ks = 0; ks < 4; ++ks)
      st = __builtin_amdgcn_mfma_f32_32x32x16_bf16(kf[ks], bqf[ks], st, 0, 0, 0);
    __builtin_amdgcn_s_setprio(0);
    // ---- causal mask (last tile only) ----
    if (diag) {
      #pragma unroll
      for (int r = 0; r < 16; ++r) {
        int key = t * 32 + (r & 3) + 8 * (r >> 2) + 4 * hi;
        if (key > q0 + col) st[r] = -INFINITY;
      }
    }
    // ---- online softmax (lane-local, exp2 domain, defer-max THR=8) ----
    float mm;
    {
      float a0 = fmaxf(fmaxf(st[0], st[1]), fmaxf(st[2], st[3]));
      float a1 = fmaxf(fmaxf(st[4], st[5]), fmaxf(st[6], st[7]));
      float a2 = fmaxf(fmaxf(st[8], st[9]), fmaxf(st[10], st[11]));
      float a3 = fmaxf(fmaxf(st[12], st[13]), fmaxf(st[14], st[15]));
      mm = fmaxf(fmaxf(a0, a1), fmaxf(a2, a3));
    }
    mm = fmaxf(mm, __shfl_xor(mm, 32));
    if (!__all(mm <= m + 8.f)) {
      float mnew = fmaxf(m, mm);
      float corr = exp2f(m - mnew);
      m = mnew;
      l *= corr;
      #pragma unroll
      for (int r = 0; r < 16; ++r) { ot0[r] *= corr; ot1[r] *= corr; }
    }
    bf16x8 pf[2];
    float psum = 0.f;
    #pragma unroll
    for (int half = 0; half < 2; ++half) {
      bf16x8 w;
      #pragma unroll
      for (int e = 0; e < 8; ++e) {
        float pv = exp2f(st[half * 8 + e] - m);
        psum += pv;
        w[e] = (__bf16)pv;
      }
      pf[half] = w;
    }
    psum += __shfl_xor(psum, 32);
    l += psum;
    // ---- PV: O^T += Vp · P^T ----
    __builtin_amdgcn_s_setprio(1);
    #pragma unroll
    for (int ks = 0; ks < 2; ++ks) {
      ot0 = __builtin_amdgcn_mfma_f32_32x32x16_bf16(vf[ks],     pf[ks], ot0, 0, 0, 0);
      ot1 = __builtin_amdgcn_mfma_f32_32x32x16_bf16(vf[2 + ks], pf[ks], ot1, 0, 0, 0);
    }
    __builtin_amdgcn_s_setprio(0);
  };

  // software pipeline: 1 tile ahead, named register sets (static indexing)
  LOADK(0, kfA); LOADV(0, vfA);
  int t = 0;
  for (; t + 1 < ntiles; t += 2) {
    LOADK(t + 1, kfB); LOADV(t + 1, vfB);
    COMPUTE(t, false, kfA, vfA);
    if (t + 2 < ntiles) { LOADK(t + 2, kfA); LOADV(t + 2, vfA); }
    COMPUTE(t + 1, t + 1 == ntiles - 1, kfB, vfB);
  }
  if (t < ntiles) COMPUTE(t, true, kfA, vfA);

  // ---- normalize + store y[B][T][C] ----
  float inv = 1.f / l;
  unsigned short* yrow = y + ((size_t)b * T_ + q0 + col) * C_ + h * D_;
  #pragma unroll
  for (int a = 0; a < 4; ++a) {
    ushort4 o4;
    o4.x = f2bf(ot0[4 * a + 0] * inv);
    o4.y = f2bf(ot0[4 * a + 1] * inv);
    o4.z = f2bf(ot0[4 * a + 2] * inv);
    o4.w = f2bf(ot0[4 * a + 3] * inv);
    *(ushort4*)(yrow + 8 * a + 4 * hi) = o4;
  }
  #pragma unroll
  for (int a = 0; a < 4; ++a) {
    ushort4 o4;
    o4.x = f2bf(ot1[4 * a + 0] * inv);
    o4.y = f2bf(ot1[4 * a + 1] * inv);
    o4.z = f2bf(ot1[4 * a + 2] * inv);
    o4.w = f2bf(ot1[4 * a + 3] * inv);
    *(ushort4*)(yrow + 32 + 8 * a + 4 * hi) = o4;
  }
}

extern "C" void kernel_launch(void* const* d_in, const int* in_sizes, int n_in,
                              void* d_out, int out_size, void* d_ws, size_t ws_size,
                              hipStream_t stream) {
  const float* x  = (const float*)d_in[0];
  const float* Wq = (const float*)d_in[1];
  const float* bq = (const float*)d_in[2];
  const float* Wk = (const float*)d_in[3];
  const float* bk = (const float*)d_in[4];
  const float* Wv = (const float*)d_in[5];
  const float* bv = (const float*)d_in[6];
  const float* Wp = (const float*)d_in[7];
  const float* bp = (const float*)d_in[8];
  float* out = (float*)d_out;

  char* ws = (char*)d_ws;
  unsigned short* xb  = (unsigned short*)ws; ws += (size_t)M_ * C_ * 2;
  unsigned short* wqt = (unsigned short*)ws; ws += (size_t)C_ * C_ * 2;
  unsigned short* wkt = (unsigned short*)ws; ws += (size_t)C_ * C_ * 2;
  unsigned short* wvt = (unsigned short*)ws; ws += (size_t)C_ * C_ * 2;
  unsigned short* wpt = (unsigned short*)ws; ws += (size_t)C_ * C_ * 2;
  unsigned short* qb  = (unsigned short*)ws; ws += (size_t)M_ * C_ * 2;
  unsigned short* kb  = (unsigned short*)ws; ws += (size_t)M_ * C_ * 2;
  unsigned short* vtb = (unsigned short*)ws; ws += (size_t)M_ * C_ * 2;
  unsigned short* yb  = (unsigned short*)ws; ws += (size_t)M_ * C_ * 2;

  cvt_f32_bf16<<<dim3((M_ * C_ / 4 + 255) / 256), dim3(256), 0, stream>>>(x, xb, M_ * C_ / 4);
  transpose_cvt<<<dim3(32, 32, 4), dim3(32, 8), 0, stream>>>(Wq, Wk, Wv, Wp, wqt, wkt, wvt, wpt);

  dim3 ggrid(C_ / 128, M_ / 128);
  const float qscale = 0.125f * 1.4426950408889634f;  // 1/sqrt(64) * log2(e): exp2-domain softmax
  gemm_bf16<0><<<ggrid, dim3(256), 0, stream>>>(xb, wqt, bq, qb, C_, C_, qscale);
  gemm_bf16<0><<<ggrid, dim3(256), 0, stream>>>(xb, wkt, bk, kb, C_, C_, 1.f);
  gemm_bf16<1><<<ggrid, dim3(256), 0, stream>>>(xb, wvt, bv, vtb, C_, C_, 1.f);

  attn5<<<dim3(1024), dim3(256), 0, stream>>>(qb, kb, vtb, yb);

  gemm_bf16<2><<<ggrid, dim3(256), 0, stream>>>(yb, wpt, bp, out, C_, C_, 1.f);
}

// Round 6
// 243.830 us; speedup vs baseline: 1.0125x; 1.0125x over previous
//
#include <hip/hip_runtime.h>
#include <hip/hip_bf16.h>

#define B_ 4
#define T_ 2048
#define C_ 1024
#define H_ 16
#define D_ 64
#define M_ (B_*T_)   // 8192

typedef __bf16 bf16x8 __attribute__((ext_vector_type(8)));
typedef float  f32x4  __attribute__((ext_vector_type(4)));
typedef float  f32x16 __attribute__((ext_vector_type(16)));

__device__ __forceinline__ unsigned short f2bf(float f) {
  unsigned u = __builtin_bit_cast(unsigned, f);
  u += 0x7FFF + ((u >> 16) & 1);   // round-to-nearest-even
  return (unsigned short)(u >> 16);
}

__device__ __forceinline__ void gload_lds16(const void* g, void* l) {
  __builtin_amdgcn_global_load_lds(
      (const __attribute__((address_space(1))) void*)g,
      (__attribute__((address_space(3))) void*)l, 16, 0, 0);
}

// ---------------- conversion: f32 -> bf16 (vectorized) ----------------
__global__ void cvt_f32_bf16(const float* __restrict__ in,
                             unsigned short* __restrict__ out, int n4) {
  int i = blockIdx.x * blockDim.x + threadIdx.x;
  if (i < n4) {
    float4 v = ((const float4*)in)[i];
    ushort4 o;
    o.x = f2bf(v.x); o.y = f2bf(v.y); o.z = f2bf(v.z); o.w = f2bf(v.w);
    ((ushort4*)out)[i] = o;
  }
}

// ------------- weight transpose + convert: W[K][N] f32 -> Wt[N][K] bf16 -------------
__global__ void transpose_cvt(const float* __restrict__ w0, const float* __restrict__ w1,
                              const float* __restrict__ w2, const float* __restrict__ w3,
                              unsigned short* __restrict__ t0, unsigned short* __restrict__ t1,
                              unsigned short* __restrict__ t2, unsigned short* __restrict__ t3) {
  __shared__ float tile[32][33];
  const float* src; unsigned short* dst;
  switch (blockIdx.z) {
    case 0: src = w0; dst = t0; break;
    case 1: src = w1; dst = t1; break;
    case 2: src = w2; dst = t2; break;
    default: src = w3; dst = t3; break;
  }
  int bx = blockIdx.x * 32;  // n base
  int by = blockIdx.y * 32;  // k base
  int tx = threadIdx.x, ty = threadIdx.y;
  #pragma unroll
  for (int j = 0; j < 4; ++j)
    tile[ty + 8*j][tx] = src[(size_t)(by + ty + 8*j) * C_ + bx + tx];
  __syncthreads();
  #pragma unroll
  for (int j = 0; j < 4; ++j)
    dst[(size_t)(bx + ty + 8*j) * C_ + by + tx] = f2bf(tile[tx][ty + 8*j]);
}

// ---------------- bf16 MFMA GEMM: A[M][K] * Bt[N][K]^T + bias, then *oscale ----------------
// MODE 0: store bf16, head-split [B][H][T][D]
// MODE 1: store bf16, head-split transposed [B][H][D][T] with key-permuted order
//         (t bits 2<->3 swapped) for direct PV A-fragment reads
// MODE 2: store f32 [M][N]                                 (final output)
template<int MODE>
__global__ __launch_bounds__(256, 2)
void gemm_bf16(const unsigned short* __restrict__ A,
               const unsigned short* __restrict__ Bt,
               const float* __restrict__ bias,
               void* __restrict__ Cout, int K, int N, float oscale)
{
  __shared__ unsigned short lsA[128 * 64];
  __shared__ unsigned short lsB[128 * 64];
  const int wave = threadIdx.x >> 6;
  const int lane = threadIdx.x & 63;
  const int rowBase = blockIdx.y * 128;
  const int colBase = blockIdx.x * 128;
  const int rowOff = (wave >> 1) * 64;
  const int colOff = (wave & 1) * 64;
  const int lr = lane & 15;
  const int lg = lane >> 4;

  f32x4 acc[4][4] = {};

  const int chunkRow = lane >> 3;
  const int srcColE  = (((lane & 7) ^ (lane >> 3)) * 8);

  for (int k0 = 0; k0 < K; k0 += 64) {
    #pragma unroll
    for (int c = 0; c < 4; ++c) {
      int chunk = c * 4 + wave;
      int r = chunk * 8 + chunkRow;
      gload_lds16(A  + (size_t)(rowBase + r) * K + k0 + srcColE, &lsA[chunk * 512]);
      gload_lds16(Bt + (size_t)(colBase + r) * K + k0 + srcColE, &lsB[chunk * 512]);
    }
    __syncthreads();
    #pragma unroll
    for (int kk = 0; kk < 2; ++kk) {
      bf16x8 af[4], bfr[4];
      const int kbyte = (kk * 32 + lg * 8) * 2;
      #pragma unroll
      for (int m = 0; m < 4; ++m) {
        int row = rowOff + m * 16 + lr;
        af[m] = *(const bf16x8*)((const char*)lsA + row * 128 + (kbyte ^ ((row & 7) << 4)));
      }
      #pragma unroll
      for (int n = 0; n < 4; ++n) {
        int row = colOff + n * 16 + lr;
        bfr[n] = *(const bf16x8*)((const char*)lsB + row * 128 + (kbyte ^ ((row & 7) << 4)));
      }
      #pragma unroll
      for (int m = 0; m < 4; ++m)
        #pragma unroll
        for (int n = 0; n < 4; ++n)
          acc[m][n] = __builtin_amdgcn_mfma_f32_16x16x32_bf16(af[m], bfr[n], acc[m][n], 0, 0, 0);
    }
    __syncthreads();
  }

  #pragma unroll
  for (int m = 0; m < 4; ++m) {
    int row0 = rowBase + rowOff + m * 16 + lg * 4;
    #pragma unroll
    for (int n = 0; n < 4; ++n) {
      int col = colBase + colOff + n * 16 + lr;
      float bs = bias[col];
      if (MODE == 1) {
        int b = row0 >> 11, t = row0 & 2047;
        int t2 = (t & ~12) | ((t & 4) << 1) | ((t & 8) >> 1);  // key-perm (bits 2<->3)
        int h = col >> 6, d = col & 63;
        ushort4 o;
        o.x = f2bf((acc[m][n][0] + bs) * oscale);
        o.y = f2bf((acc[m][n][1] + bs) * oscale);
        o.z = f2bf((acc[m][n][2] + bs) * oscale);
        o.w = f2bf((acc[m][n][3] + bs) * oscale);
        *(ushort4*)((unsigned short*)Cout + (((size_t)b * H_ + h) * D_ + d) * T_ + t2) = o;
      } else {
        #pragma unroll
        for (int j = 0; j < 4; ++j) {
          float v = (acc[m][n][j] + bs) * oscale;
          int r = row0 + j;
          if (MODE == 2) {
            ((float*)Cout)[(size_t)r * N + col] = v;
          } else {
            int b = r >> 11, t = r & 2047;
            int h = col >> 6, d = col & 63;
            ((unsigned short*)Cout)[((((size_t)b * H_ + h) * T_ + t) << 6) + d] = f2bf(v);
          }
        }
      }
    }
  }
}

// ---------------- causal flash attention: barrier-free + intra-wave software pipeline ----
// q,k: [B][H][T][D] bf16 (q pre-scaled by log2e/sqrt(D)); vp: [B][H][D][T] bf16 key-permuted
// (bits 2<->3 of t swapped) so global layout == MFMA A-fragment layout; y: [B][T][C] bf16.
// One wave per 32-row q-tile; no LDS, no __syncthreads.
// Pipeline per iteration t: issue QK^T(t+1) (two independent 2-chains) -> issue K-load(t+2)
// -> softmax(t) on VALU/TRANS (overlaps matrix pipe) -> issue PV(t) -> issue V-load(t+1)
// -> fold S = SN0+SN1. Swapped QK^T / PV keeps softmax fully lane-local.
__global__ __launch_bounds__(256, 2)
void attn6(const unsigned short* __restrict__ q,
           const unsigned short* __restrict__ k,
           const unsigned short* __restrict__ vp,
           unsigned short* __restrict__ y)
{
  const int wave = threadIdx.x >> 6;
  const int lane = threadIdx.x & 63;
  const int col  = lane & 31;   // query index within 32 (and K-row / V-d-row index)
  const int hi   = lane >> 5;

  // block decode: XCD-local heads, longest q-tiles first, 4 consecutive qt per block
  const int bid = blockIdx.x;            // 0..1023
  const int xcd = bid & 7;
  const int idx = bid >> 3;              // 0..127
  const int qtg = 15 - (idx >> 3);       // 15..0  (longest first)
  const int bh  = xcd * 8 + (idx & 7);   // 8 heads per XCD
  const int b = bh >> 4, h = bh & 15;
  const int qt  = qtg * 4 + wave;        // 0..63
  const int q0  = qt * 32;
  const int ntiles = qt + 1;             // 32-key tiles

  const unsigned short* qh = q  + (size_t)bh * T_ * D_;
  const unsigned short* kh = k  + (size_t)bh * T_ * D_;
  const unsigned short* vh = vp + (size_t)bh * D_ * T_;

  // Q B-fragments: bqf[ks] = Q[q0+col][ks*16 + hi*8 + e]
  bf16x8 bqf[4];
  {
    const unsigned short* qrow = qh + (size_t)(q0 + col) * D_ + hi * 8;
    #pragma unroll
    for (int ks = 0; ks < 4; ++ks) bqf[ks] = *(const bf16x8*)(qrow + ks * 16);
  }

  f32x16 ot0 = {}, ot1 = {};
  float m = -INFINITY, l = 0.f;
  const f32x16 zc = {};                  // persistent zero C-operand (no per-tile zero-init)

  bf16x8 kfA[4], kfB[4], vf[4];
  f32x16 S, SN0, SN1;
  bf16x8 pf0, pf1;

  // incremental load pointers
  const unsigned short* kbase = kh + (size_t)col * D_ + hi * 8;
  const unsigned short* vbase = vh + (size_t)col * T_ + hi * 8;
  const unsigned short* kld = kbase + 2 * 32 * D_;   // next K load: tile 2
  const unsigned short* vld = vbase + 32;            // next V load: tile 1

  // prologue: K0, V0, K1; S = QK^T(tile 0)
  #pragma unroll
  for (int ks = 0; ks < 4; ++ks) kfA[ks] = *(const bf16x8*)(kbase + ks * 16);
  #pragma unroll
  for (int dt = 0; dt < 2; ++dt)
    #pragma unroll
    for (int ks = 0; ks < 2; ++ks)
      vf[dt * 2 + ks] = *(const bf16x8*)(vbase + dt * 32 * T_ + ks * 16);
  if (ntiles > 1) {
    #pragma unroll
    for (int ks = 0; ks < 4; ++ks) kfB[ks] = *(const bf16x8*)(kbase + 32 * D_ + ks * 16);
  }
  {
    f32x16 p0 = __builtin_amdgcn_mfma_f32_32x32x16_bf16(kfA[0], bqf[0], zc, 0, 0, 0);
    f32x16 p1 = __builtin_amdgcn_mfma_f32_32x32x16_bf16(kfA[1], bqf[1], zc, 0, 0, 0);
    p0 = __builtin_amdgcn_mfma_f32_32x32x16_bf16(kfA[2], bqf[2], p0, 0, 0, 0);
    p1 = __builtin_amdgcn_mfma_f32_32x32x16_bf16(kfA[3], bqf[3], p1, 0, 0, 0);
    S = p0 + p1;
  }

  int t = 0;

  auto SOFTMAX = [&](bool diag) {
    if (diag) {
      #pragma unroll
      for (int r = 0; r < 16; ++r) {
        int key = t * 32 + (r & 3) + 8 * (r >> 2) + 4 * hi;
        if (key > q0 + col) S[r] = -INFINITY;
      }
    }
    float a0 = fmaxf(fmaxf(S[0], S[1]), fmaxf(S[2], S[3]));
    float a1 = fmaxf(fmaxf(S[4], S[5]), fmaxf(S[6], S[7]));
    float a2 = fmaxf(fmaxf(S[8], S[9]), fmaxf(S[10], S[11]));
    float a3 = fmaxf(fmaxf(S[12], S[13]), fmaxf(S[14], S[15]));
    float mm = fmaxf(fmaxf(a0, a1), fmaxf(a2, a3));
    mm = fmaxf(mm, __shfl_xor(mm, 32));
    if (!__all(mm <= m + 8.f)) {           // defer-max THR=8 (exp2 domain)
      float mnew = fmaxf(m, mm);
      float corr = exp2f(m - mnew);
      m = mnew;
      l *= corr;
      #pragma unroll
      for (int r = 0; r < 16; ++r) { ot0[r] *= corr; ot1[r] *= corr; }
    }
    float psum = 0.f;
    {
      bf16x8 w;
      #pragma unroll
      for (int e = 0; e < 8; ++e) {
        float pv = exp2f(S[e] - m);
        psum += pv;
        w[e] = (__bf16)pv;
      }
      pf0 = w;
    }
    {
      bf16x8 w;
      #pragma unroll
      for (int e = 0; e < 8; ++e) {
        float pv = exp2f(S[8 + e] - m);
        psum += pv;
        w[e] = (__bf16)pv;
      }
      pf1 = w;
    }
    psum += __shfl_xor(psum, 32);
    l += psum;
  };

  auto PVSTEP = [&]() {
    __builtin_amdgcn_s_setprio(1);
    ot0 = __builtin_amdgcn_mfma_f32_32x32x16_bf16(vf[0], pf0, ot0, 0, 0, 0);
    ot1 = __builtin_amdgcn_mfma_f32_32x32x16_bf16(vf[2], pf0, ot1, 0, 0, 0);
    ot0 = __builtin_amdgcn_mfma_f32_32x32x16_bf16(vf[1], pf1, ot0, 0, 0, 0);
    ot1 = __builtin_amdgcn_mfma_f32_32x32x16_bf16(vf[3], pf1, ot1, 0, 0, 0);
    __builtin_amdgcn_s_setprio(0);
  };

  // one pipelined iteration: consumes S (tile t), K[t+1] in KN; loads K[t+2] into KL,
  // V[t+1] into vf; leaves S = tile t+1.
#define STEP(KN, KL)                                                              \
  do {                                                                            \
    __builtin_amdgcn_s_setprio(1);                                                \
    SN0 = __builtin_amdgcn_mfma_f32_32x32x16_bf16(KN[0], bqf[0], zc, 0, 0, 0);    \
    SN1 = __builtin_amdgcn_mfma_f32_32x32x16_bf16(KN[1], bqf[1], zc, 0, 0, 0);    \
    SN0 = __builtin_amdgcn_mfma_f32_32x32x16_bf16(KN[2], bqf[2], SN0, 0, 0, 0);   \
    SN1 = __builtin_amdgcn_mfma_f32_32x32x16_bf16(KN[3], bqf[3], SN1, 0, 0, 0);   \
    __builtin_amdgcn_s_setprio(0);                                                \
    if (t + 2 < ntiles) {                                                         \
      _Pragma("unroll")                                                           \
      for (int ks = 0; ks < 4; ++ks) KL[ks] = *(const bf16x8*)(kld + ks * 16);    \
      kld += 32 * D_;                                                             \
    }                                                                             \
    SOFTMAX(false);                                                               \
    PVSTEP();                                                                     \
    _Pragma("unroll")                                                             \
    for (int dt = 0; dt < 2; ++dt) {                                              \
      _Pragma("unroll")                                                           \
      for (int ks = 0; ks < 2; ++ks)                                              \
        vf[dt * 2 + ks] = *(const bf16x8*)(vld + dt * 32 * T_ + ks * 16);         \
    }                                                                             \
    vld += 32;                                                                    \
    S = SN0 + SN1;                                                                \
    ++t;                                                                          \
  } while (0)

  while (t + 1 < ntiles) {
    STEP(kfB, kfA);
    if (t + 1 < ntiles) STEP(kfA, kfB);
  }
#undef STEP

  // final tile (diagonal): softmax with mask + PV
  SOFTMAX(true);
  PVSTEP();

  // ---- normalize + store y[B][T][C] ----
  float inv = 1.f / l;
  unsigned short* yrow = y + ((size_t)b * T_ + q0 + col) * C_ + h * D_;
  #pragma unroll
  for (int a = 0; a < 4; ++a) {
    ushort4 o4;
    o4.x = f2bf(ot0[4 * a + 0] * inv);
    o4.y = f2bf(ot0[4 * a + 1] * inv);
    o4.z = f2bf(ot0[4 * a + 2] * inv);
    o4.w = f2bf(ot0[4 * a + 3] * inv);
    *(ushort4*)(yrow + 8 * a + 4 * hi) = o4;
  }
  #pragma unroll
  for (int a = 0; a < 4; ++a) {
    ushort4 o4;
    o4.x = f2bf(ot1[4 * a + 0] * inv);
    o4.y = f2bf(ot1[4 * a + 1] * inv);
    o4.z = f2bf(ot1[4 * a + 2] * inv);
    o4.w = f2bf(ot1[4 * a + 3] * inv);
    *(ushort4*)(yrow + 32 + 8 * a + 4 * hi) = o4;
  }
}

extern "C" void kernel_launch(void* const* d_in, const int* in_sizes, int n_in,
                              void* d_out, int out_size, void* d_ws, size_t ws_size,
                              hipStream_t stream) {
  const float* x  = (const float*)d_in[0];
  const float* Wq = (const float*)d_in[1];
  const float* bq = (const float*)d_in[2];
  const float* Wk = (const float*)d_in[3];
  const float* bk = (const float*)d_in[4];
  const float* Wv = (const float*)d_in[5];
  const float* bv = (const float*)d_in[6];
  const float* Wp = (const float*)d_in[7];
  const float* bp = (const float*)d_in[8];
  float* out = (float*)d_out;

  char* ws = (char*)d_ws;
  unsigned short* xb  = (unsigned short*)ws; ws += (size_t)M_ * C_ * 2;
  unsigned short* wqt = (unsigned short*)ws; ws += (size_t)C_ * C_ * 2;
  unsigned short* wkt = (unsigned short*)ws; ws += (size_t)C_ * C_ * 2;
  unsigned short* wvt = (unsigned short*)ws; ws += (size_t)C_ * C_ * 2;
  unsigned short* wpt = (unsigned short*)ws; ws += (size_t)C_ * C_ * 2;
  unsigned short* qb  = (unsigned short*)ws; ws += (size_t)M_ * C_ * 2;
  unsigned short* kb  = (unsigned short*)ws; ws += (size_t)M_ * C_ * 2;
  unsigned short* vtb = (unsigned short*)ws; ws += (size_t)M_ * C_ * 2;
  unsigned short* yb  = (unsigned short*)ws; ws += (size_t)M_ * C_ * 2;

  cvt_f32_bf16<<<dim3((M_ * C_ / 4 + 255) / 256), dim3(256), 0, stream>>>(x, xb, M_ * C_ / 4);
  transpose_cvt<<<dim3(32, 32, 4), dim3(32, 8), 0, stream>>>(Wq, Wk, Wv, Wp, wqt, wkt, wvt, wpt);

  dim3 ggrid(C_ / 128, M_ / 128);
  const float qscale = 0.125f * 1.4426950408889634f;  // 1/sqrt(64) * log2(e): exp2-domain softmax
  gemm_bf16<0><<<ggrid, dim3(256), 0, stream>>>(xb, wqt, bq, qb, C_, C_, qscale);
  gemm_bf16<0><<<ggrid, dim3(256), 0, stream>>>(xb, wkt, bk, kb, C_, C_, 1.f);
  gemm_bf16<1><<<ggrid, dim3(256), 0, stream>>>(xb, wvt, bv, vtb, C_, C_, 1.f);

  attn6<<<dim3(1024), dim3(256), 0, stream>>>(qb, kb, vtb, yb);

  gemm_bf16<2><<<ggrid, dim3(256), 0, stream>>>(yb, wpt, bp, out, C_, C_, 1.f);
}

// Round 7
// 235.659 us; speedup vs baseline: 1.0476x; 1.0347x over previous
//
#include <hip/hip_runtime.h>
#include <hip/hip_bf16.h>

#define B_ 4
#define T_ 2048
#define C_ 1024
#define H_ 16
#define D_ 64
#define M_ (B_*T_)   // 8192

typedef __bf16 bf16x8 __attribute__((ext_vector_type(8)));
typedef float  f32x4  __attribute__((ext_vector_type(4)));
typedef float  f32x16 __attribute__((ext_vector_type(16)));

__device__ __forceinline__ unsigned short f2bf(float f) {
  unsigned u = __builtin_bit_cast(unsigned, f);
  u += 0x7FFF + ((u >> 16) & 1);   // round-to-nearest-even
  return (unsigned short)(u >> 16);
}

__device__ __forceinline__ void gload_lds16(const void* g, void* l) {
  __builtin_amdgcn_global_load_lds(
      (const __attribute__((address_space(1))) void*)g,
      (__attribute__((address_space(3))) void*)l, 16, 0, 0);
}

// ---------------- conversion: f32 -> bf16 (vectorized) ----------------
__global__ void cvt_f32_bf16(const float* __restrict__ in,
                             unsigned short* __restrict__ out, int n4) {
  int i = blockIdx.x * blockDim.x + threadIdx.x;
  if (i < n4) {
    float4 v = ((const float4*)in)[i];
    ushort4 o;
    o.x = f2bf(v.x); o.y = f2bf(v.y); o.z = f2bf(v.z); o.w = f2bf(v.w);
    ((ushort4*)out)[i] = o;
  }
}

// ------------- weight transpose + convert: W[K][N] f32 -> Wt[N][K] bf16 -------------
// z = 0,1,2 -> rows 0/1024/2048 of concatenated wqkvt [3072][1024]; z = 3 -> wpt
__global__ void transpose_cvt(const float* __restrict__ w0, const float* __restrict__ w1,
                              const float* __restrict__ w2, const float* __restrict__ w3,
                              unsigned short* __restrict__ tqkv,
                              unsigned short* __restrict__ tp) {
  __shared__ float tile[32][33];
  const float* src; unsigned short* dst;
  switch (blockIdx.z) {
    case 0: src = w0; dst = tqkv; break;
    case 1: src = w1; dst = tqkv + (size_t)C_ * C_; break;
    case 2: src = w2; dst = tqkv + (size_t)2 * C_ * C_; break;
    default: src = w3; dst = tp; break;
  }
  int bx = blockIdx.x * 32;  // n base
  int by = blockIdx.y * 32;  // k base
  int tx = threadIdx.x, ty = threadIdx.y;
  #pragma unroll
  for (int j = 0; j < 4; ++j)
    tile[ty + 8*j][tx] = src[(size_t)(by + ty + 8*j) * C_ + bx + tx];
  __syncthreads();
  #pragma unroll
  for (int j = 0; j < 4; ++j)
    dst[(size_t)(bx + ty + 8*j) * C_ + by + tx] = f2bf(tile[tx][ty + 8*j]);
}

// ---------------- fused QKV GEMM: xb[M][K] @ wqkvt[3N][K]^T ----------------
// column block 0..7 -> Q (scaled, [B][H][T][D]); 8..15 -> K ([B][H][T][D]);
// 16..23 -> V (key-permuted transposed [B][H][D][T], t bits 2<->3 swapped)
__global__ __launch_bounds__(256, 2)
void gemm_qkv(const unsigned short* __restrict__ A,
              const unsigned short* __restrict__ Bt,
              const float* __restrict__ bq, const float* __restrict__ bk,
              const float* __restrict__ bv,
              unsigned short* __restrict__ qout, unsigned short* __restrict__ kout,
              unsigned short* __restrict__ vout, float qscale)
{
  __shared__ unsigned short lsA[128 * 64];
  __shared__ unsigned short lsB[128 * 64];
  const int wave = threadIdx.x >> 6;
  const int lane = threadIdx.x & 63;
  const int rowBase = blockIdx.y * 128;
  const int colBase = blockIdx.x * 128;
  const int rowOff = (wave >> 1) * 64;
  const int colOff = (wave & 1) * 64;
  const int lr = lane & 15;
  const int lg = lane >> 4;

  f32x4 acc[4][4] = {};

  const int chunkRow = lane >> 3;
  const int srcColE  = (((lane & 7) ^ (lane >> 3)) * 8);

  for (int k0 = 0; k0 < C_; k0 += 64) {
    #pragma unroll
    for (int c = 0; c < 4; ++c) {
      int chunk = c * 4 + wave;
      int r = chunk * 8 + chunkRow;
      gload_lds16(A  + (size_t)(rowBase + r) * C_ + k0 + srcColE, &lsA[chunk * 512]);
      gload_lds16(Bt + (size_t)(colBase + r) * C_ + k0 + srcColE, &lsB[chunk * 512]);
    }
    __syncthreads();
    #pragma unroll
    for (int kk = 0; kk < 2; ++kk) {
      bf16x8 af[4], bfr[4];
      const int kbyte = (kk * 32 + lg * 8) * 2;
      #pragma unroll
      for (int m = 0; m < 4; ++m) {
        int row = rowOff + m * 16 + lr;
        af[m] = *(const bf16x8*)((const char*)lsA + row * 128 + (kbyte ^ ((row & 7) << 4)));
      }
      #pragma unroll
      for (int n = 0; n < 4; ++n) {
        int row = colOff + n * 16 + lr;
        bfr[n] = *(const bf16x8*)((const char*)lsB + row * 128 + (kbyte ^ ((row & 7) << 4)));
      }
      #pragma unroll
      for (int m = 0; m < 4; ++m)
        #pragma unroll
        for (int n = 0; n < 4; ++n)
          acc[m][n] = __builtin_amdgcn_mfma_f32_16x16x32_bf16(af[m], bfr[n], acc[m][n], 0, 0, 0);
    }
    __syncthreads();
  }

  const int mid = colBase >> 10;                 // 0=Q 1=K 2=V (block-uniform)
  const float* bias = (mid == 0) ? bq : (mid == 1) ? bk : bv;
  const float oscale = (mid == 0) ? qscale : 1.f;
  unsigned short* outp = (mid == 0) ? qout : (mid == 1) ? kout : vout;

  #pragma unroll
  for (int m = 0; m < 4; ++m) {
    int row0 = rowBase + rowOff + m * 16 + lg * 4;
    #pragma unroll
    for (int n = 0; n < 4; ++n) {
      int col = colBase + colOff + n * 16 + lr;
      int ncol = col & 1023;
      float bs = bias[ncol];
      int h = ncol >> 6, d = ncol & 63;
      if (mid == 2) {
        int b = row0 >> 11, t = row0 & 2047;
        int t2 = (t & ~12) | ((t & 4) << 1) | ((t & 8) >> 1);  // key-perm (bits 2<->3)
        ushort4 o;
        o.x = f2bf(acc[m][n][0] + bs);
        o.y = f2bf(acc[m][n][1] + bs);
        o.z = f2bf(acc[m][n][2] + bs);
        o.w = f2bf(acc[m][n][3] + bs);
        *(ushort4*)(outp + (((size_t)b * H_ + h) * D_ + d) * T_ + t2) = o;
      } else {
        #pragma unroll
        for (int j = 0; j < 4; ++j) {
          int r = row0 + j;
          int b = r >> 11, t = r & 2047;
          outp[((((size_t)b * H_ + h) * T_ + t) << 6) + d] = f2bf((acc[m][n][j] + bs) * oscale);
        }
      }
    }
  }
}

// ---------------- final projection GEMM: yb[M][K] @ wpt[N][K]^T -> f32 ----------------
__global__ __launch_bounds__(256, 2)
void gemm_proj(const unsigned short* __restrict__ A,
               const unsigned short* __restrict__ Bt,
               const float* __restrict__ bias,
               float* __restrict__ Cout)
{
  __shared__ unsigned short lsA[128 * 64];
  __shared__ unsigned short lsB[128 * 64];
  const int wave = threadIdx.x >> 6;
  const int lane = threadIdx.x & 63;
  const int rowBase = blockIdx.y * 128;
  const int colBase = blockIdx.x * 128;
  const int rowOff = (wave >> 1) * 64;
  const int colOff = (wave & 1) * 64;
  const int lr = lane & 15;
  const int lg = lane >> 4;

  f32x4 acc[4][4] = {};

  const int chunkRow = lane >> 3;
  const int srcColE  = (((lane & 7) ^ (lane >> 3)) * 8);

  for (int k0 = 0; k0 < C_; k0 += 64) {
    #pragma unroll
    for (int c = 0; c < 4; ++c) {
      int chunk = c * 4 + wave;
      int r = chunk * 8 + chunkRow;
      gload_lds16(A  + (size_t)(rowBase + r) * C_ + k0 + srcColE, &lsA[chunk * 512]);
      gload_lds16(Bt + (size_t)(colBase + r) * C_ + k0 + srcColE, &lsB[chunk * 512]);
    }
    __syncthreads();
    #pragma unroll
    for (int kk = 0; kk < 2; ++kk) {
      bf16x8 af[4], bfr[4];
      const int kbyte = (kk * 32 + lg * 8) * 2;
      #pragma unroll
      for (int m = 0; m < 4; ++m) {
        int row = rowOff + m * 16 + lr;
        af[m] = *(const bf16x8*)((const char*)lsA + row * 128 + (kbyte ^ ((row & 7) << 4)));
      }
      #pragma unroll
      for (int n = 0; n < 4; ++n) {
        int row = colOff + n * 16 + lr;
        bfr[n] = *(const bf16x8*)((const char*)lsB + row * 128 + (kbyte ^ ((row & 7) << 4)));
      }
      #pragma unroll
      for (int m = 0; m < 4; ++m)
        #pragma unroll
        for (int n = 0; n < 4; ++n)
          acc[m][n] = __builtin_amdgcn_mfma_f32_16x16x32_bf16(af[m], bfr[n], acc[m][n], 0, 0, 0);
    }
    __syncthreads();
  }

  #pragma unroll
  for (int m = 0; m < 4; ++m) {
    int row0 = rowBase + rowOff + m * 16 + lg * 4;
    #pragma unroll
    for (int n = 0; n < 4; ++n) {
      int col = colBase + colOff + n * 16 + lr;
      float bs = bias[col];
      #pragma unroll
      for (int j = 0; j < 4; ++j)
        Cout[(size_t)(row0 + j) * C_ + col] = acc[m][n][j] + bs;
    }
  }
}

// ---------------- causal flash attention: paired q-tiles, barrier-free ----------------
// q,k: [B][H][T][D] bf16 (q pre-scaled by log2e/sqrt(D)); vp: [B][H][D][T] bf16 key-permuted
// (bits 2<->3 of t swapped) so global layout == MFMA A-fragment layout; y: [B][T][C] bf16.
// Each wave processes TWO q-tiles (pair p and 63-p) sequentially -> exactly 65 tile-steps
// per wave, perfectly uniform (no tail). 2048 waves, no LDS, no __syncthreads.
// Register pipeline per tile t: issue QK^T(t+1) (4-chain) -> prefetch K(t+2) -> softmax(t)
// on VALU/TRANS (overlaps matrix pipe) -> PV(t) -> load V(t+1).
__global__ __launch_bounds__(256, 2)
void attn7(const unsigned short* __restrict__ q,
           const unsigned short* __restrict__ k,
           const unsigned short* __restrict__ vp,
           unsigned short* __restrict__ y)
{
  const int wave = threadIdx.x >> 6;
  const int lane = threadIdx.x & 63;
  const int col  = lane & 31;   // query index within 32 (and K-row / V-d-row index)
  const int hi   = lane >> 5;

  // decode: 512 blocks. xcd-local heads; pair index per wave.
  const int bid = blockIdx.x;            // 0..511
  const int xcd = bid & 7;
  const int idx = bid >> 3;              // 0..63
  const int bh  = xcd * 8 + (idx & 7);   // 8 heads per XCD (4MB K/V working set = 1 L2)
  const int pg  = idx >> 3;              // 0..7
  const int pair = pg * 4 + wave;        // 0..31
  const int b = bh >> 4, h = bh & 15;

  const unsigned short* qh = q  + (size_t)bh * T_ * D_;
  const unsigned short* kh = k  + (size_t)bh * T_ * D_;
  const unsigned short* vh = vp + (size_t)bh * D_ * T_;

  const f32x16 zc = {};                  // persistent zero C-operand

  #pragma unroll 1
  for (int ph = 0; ph < 2; ++ph) {
    const int qt = ph ? (63 - pair) : pair;
    const int q0 = qt * 32;
    const int ntiles = qt + 1;           // 32-key tiles

    // Q B-fragments: bqf[ks] = Q[q0+col][ks*16 + hi*8 + e]
    bf16x8 bqf[4];
    {
      const unsigned short* qrow = qh + (size_t)(q0 + col) * D_ + hi * 8;
      #pragma unroll
      for (int ks = 0; ks < 4; ++ks) bqf[ks] = *(const bf16x8*)(qrow + ks * 16);
    }

    f32x16 ot0 = {}, ot1 = {};
    float m = -INFINITY, l = 0.f;

    bf16x8 kfA[4], kfB[4], vf[4];
    f32x16 S0, S1;
    bf16x8 pf0, pf1;

    const unsigned short* kbase = kh + (size_t)col * D_ + hi * 8;
    const unsigned short* vbase = vh + (size_t)col * T_ + hi * 8;
    const unsigned short* kld = kbase + 2 * 32 * D_;   // next K load: tile 2
    const unsigned short* vld = vbase + 32;            // next V load: tile 1

    // prologue: K0, V0, K1; S0 = QK^T(tile 0)
    #pragma unroll
    for (int ks = 0; ks < 4; ++ks) kfA[ks] = *(const bf16x8*)(kbase + ks * 16);
    #pragma unroll
    for (int dt = 0; dt < 2; ++dt)
      #pragma unroll
      for (int ks = 0; ks < 2; ++ks)
        vf[dt * 2 + ks] = *(const bf16x8*)(vbase + dt * 32 * T_ + ks * 16);
    if (ntiles > 1) {
      #pragma unroll
      for (int ks = 0; ks < 4; ++ks) kfB[ks] = *(const bf16x8*)(kbase + 32 * D_ + ks * 16);
    }
    S0 = __builtin_amdgcn_mfma_f32_32x32x16_bf16(kfA[0], bqf[0], zc, 0, 0, 0);
    S0 = __builtin_amdgcn_mfma_f32_32x32x16_bf16(kfA[1], bqf[1], S0, 0, 0, 0);
    S0 = __builtin_amdgcn_mfma_f32_32x32x16_bf16(kfA[2], bqf[2], S0, 0, 0, 0);
    S0 = __builtin_amdgcn_mfma_f32_32x32x16_bf16(kfA[3], bqf[3], S0, 0, 0, 0);

    int t = 0;

    auto SOFTMAX = [&](f32x16& S, bool diag) {
      if (diag) {
        #pragma unroll
        for (int r = 0; r < 16; ++r) {
          int key = t * 32 + (r & 3) + 8 * (r >> 2) + 4 * hi;
          if (key > q0 + col) S[r] = -INFINITY;
        }
      }
      float a0 = fmaxf(fmaxf(S[0], S[1]), fmaxf(S[2], S[3]));
      float a1 = fmaxf(fmaxf(S[4], S[5]), fmaxf(S[6], S[7]));
      float a2 = fmaxf(fmaxf(S[8], S[9]), fmaxf(S[10], S[11]));
      float a3 = fmaxf(fmaxf(S[12], S[13]), fmaxf(S[14], S[15]));
      float mm = fmaxf(fmaxf(a0, a1), fmaxf(a2, a3));
      mm = fmaxf(mm, __shfl_xor(mm, 32));
      if (!__all(mm <= m + 8.f)) {           // defer-max THR=8 (exp2 domain)
        float mnew = fmaxf(m, mm);
        float corr = exp2f(m - mnew);
        m = mnew;
        l *= corr;
        #pragma unroll
        for (int r = 0; r < 16; ++r) { ot0[r] *= corr; ot1[r] *= corr; }
      }
      float psum = 0.f;
      {
        bf16x8 w;
        #pragma unroll
        for (int e = 0; e < 8; ++e) {
          float pv = exp2f(S[e] - m);
          psum += pv;
          w[e] = (__bf16)pv;
        }
        pf0 = w;
      }
      {
        bf16x8 w;
        #pragma unroll
        for (int e = 0; e < 8; ++e) {
          float pv = exp2f(S[8 + e] - m);
          psum += pv;
          w[e] = (__bf16)pv;
        }
        pf1 = w;
      }
      psum += __shfl_xor(psum, 32);
      l += psum;
    };

    auto PVSTEP = [&]() {
      __builtin_amdgcn_s_setprio(1);
      ot0 = __builtin_amdgcn_mfma_f32_32x32x16_bf16(vf[0], pf0, ot0, 0, 0, 0);
      ot1 = __builtin_amdgcn_mfma_f32_32x32x16_bf16(vf[2], pf0, ot1, 0, 0, 0);
      ot0 = __builtin_amdgcn_mfma_f32_32x32x16_bf16(vf[1], pf1, ot0, 0, 0, 0);
      ot1 = __builtin_amdgcn_mfma_f32_32x32x16_bf16(vf[3], pf1, ot1, 0, 0, 0);
      __builtin_amdgcn_s_setprio(0);
    };

    // one pipelined iteration: consumes SCUR (tile t), K[t+1] in KN; produces SNEW (tile
    // t+1); prefetches K(t+2) into KL and V(t+1) into vf.
#define STEP(KN, KL, SCUR, SNEW)                                                    \
    do {                                                                            \
      __builtin_amdgcn_s_setprio(1);                                                \
      SNEW = __builtin_amdgcn_mfma_f32_32x32x16_bf16(KN[0], bqf[0], zc,   0, 0, 0); \
      SNEW = __builtin_amdgcn_mfma_f32_32x32x16_bf16(KN[1], bqf[1], SNEW, 0, 0, 0); \
      SNEW = __builtin_amdgcn_mfma_f32_32x32x16_bf16(KN[2], bqf[2], SNEW, 0, 0, 0); \
      SNEW = __builtin_amdgcn_mfma_f32_32x32x16_bf16(KN[3], bqf[3], SNEW, 0, 0, 0); \
      __builtin_amdgcn_s_setprio(0);                                                \
      if (t + 2 < ntiles) {                                                         \
        _Pragma("unroll")                                                           \
        for (int ks = 0; ks < 4; ++ks) KL[ks] = *(const bf16x8*)(kld + ks * 16);    \
        kld += 32 * D_;                                                             \
      }                                                                             \
      SOFTMAX(SCUR, false);                                                         \
      PVSTEP();                                                                     \
      _Pragma("unroll")                                                             \
      for (int dt = 0; dt < 2; ++dt) {                                              \
        _Pragma("unroll")                                                           \
        for (int ks = 0; ks < 2; ++ks)                                              \
          vf[dt * 2 + ks] = *(const bf16x8*)(vld + dt * 32 * T_ + ks * 16);         \
      }                                                                             \
      vld += 32;                                                                    \
      ++t;                                                                          \
    } while (0)

    if (ntiles == 1) {
      SOFTMAX(S0, true);
      PVSTEP();
    } else {
      bool done = false;
      while (!done) {
        STEP(kfB, kfA, S0, S1);
        if (t + 1 >= ntiles) { SOFTMAX(S1, true); PVSTEP(); done = true; }
        else {
          STEP(kfA, kfB, S1, S0);
          if (t + 1 >= ntiles) { SOFTMAX(S0, true); PVSTEP(); done = true; }
        }
      }
    }
#undef STEP

    // ---- normalize + store y[B][T][C] ----
    float inv = 1.f / l;
    unsigned short* yrow = y + ((size_t)b * T_ + q0 + col) * C_ + h * D_;
    #pragma unroll
    for (int a = 0; a < 4; ++a) {
      ushort4 o4;
      o4.x = f2bf(ot0[4 * a + 0] * inv);
      o4.y = f2bf(ot0[4 * a + 1] * inv);
      o4.z = f2bf(ot0[4 * a + 2] * inv);
      o4.w = f2bf(ot0[4 * a + 3] * inv);
      *(ushort4*)(yrow + 8 * a + 4 * hi) = o4;
    }
    #pragma unroll
    for (int a = 0; a < 4; ++a) {
      ushort4 o4;
      o4.x = f2bf(ot1[4 * a + 0] * inv);
      o4.y = f2bf(ot1[4 * a + 1] * inv);
      o4.z = f2bf(ot1[4 * a + 2] * inv);
      o4.w = f2bf(ot1[4 * a + 3] * inv);
      *(ushort4*)(yrow + 32 + 8 * a + 4 * hi) = o4;
    }
  }
}

extern "C" void kernel_launch(void* const* d_in, const int* in_sizes, int n_in,
                              void* d_out, int out_size, void* d_ws, size_t ws_size,
                              hipStream_t stream) {
  const float* x  = (const float*)d_in[0];
  const float* Wq = (const float*)d_in[1];
  const float* bq = (const float*)d_in[2];
  const float* Wk = (const float*)d_in[3];
  const float* bk = (const float*)d_in[4];
  const float* Wv = (const float*)d_in[5];
  const float* bv = (const float*)d_in[6];
  const float* Wp = (const float*)d_in[7];
  const float* bp = (const float*)d_in[8];
  float* out = (float*)d_out;

  char* ws = (char*)d_ws;
  unsigned short* xb    = (unsigned short*)ws; ws += (size_t)M_ * C_ * 2;
  unsigned short* wqkvt = (unsigned short*)ws; ws += (size_t)3 * C_ * C_ * 2;
  unsigned short* wpt   = (unsigned short*)ws; ws += (size_t)C_ * C_ * 2;
  unsigned short* qb    = (unsigned short*)ws; ws += (size_t)M_ * C_ * 2;
  unsigned short* kb    = (unsigned short*)ws; ws += (size_t)M_ * C_ * 2;
  unsigned short* vtb   = (unsigned short*)ws; ws += (size_t)M_ * C_ * 2;
  unsigned short* yb    = (unsigned short*)ws; ws += (size_t)M_ * C_ * 2;

  cvt_f32_bf16<<<dim3((M_ * C_ / 4 + 255) / 256), dim3(256), 0, stream>>>(x, xb, M_ * C_ / 4);
  transpose_cvt<<<dim3(32, 32, 4), dim3(32, 8), 0, stream>>>(Wq, Wk, Wv, Wp, wqkvt, wpt);

  const float qscale = 0.125f * 1.4426950408889634f;  // 1/sqrt(64) * log2(e)
  gemm_qkv<<<dim3(3 * C_ / 128, M_ / 128), dim3(256), 0, stream>>>(
      xb, wqkvt, bq, bk, bv, qb, kb, vtb, qscale);

  attn7<<<dim3(512), dim3(256), 0, stream>>>(qb, kb, vtb, yb);

  gemm_proj<<<dim3(C_ / 128, M_ / 128), dim3(256), 0, stream>>>(yb, wpt, bp, out);
}